// Round 10
// baseline (149.039 us; speedup 1.0000x reference)
//
#include <hip/hip_runtime.h>

typedef unsigned short u16;
typedef unsigned int u32;
typedef __bf16 bf16x8 __attribute__((ext_vector_type(8)));
typedef float f32x4 __attribute__((ext_vector_type(4)));
typedef u16 u16x8 __attribute__((ext_vector_type(8)));
typedef u16 u16x4 __attribute__((ext_vector_type(4)));
typedef u32 u32x2 __attribute__((ext_vector_type(2)));

#define NH 16
#define DKK 64
#define SQ 2048
#define DD 1024

#define AS1 __attribute__((address_space(1)))
#define AS3 __attribute__((address_space(3)))

// softmax scale folded with log2(e): (1/8) * 1.44269504
#define QSCALE 0.1803368925f

__device__ inline u16 f2bf(float f) {
  union { float f; u32 u; } v; v.f = f;
  u32 u = v.u;
  u += 0x7FFFu + ((u >> 16) & 1u);
  return (u16)(u >> 16);
}

__device__ __forceinline__ u32 cvtpk(float lo, float hi) {
  u32 r;
  asm("v_cvt_pk_bf16_f32 %0, %1, %2" : "=v"(r) : "v"(lo), "v"(hi));
  return r;
}

__device__ inline u16x8 cvt8(const float* p) {
  float4 a = *(const float4*)p;
  float4 b = *(const float4*)(p + 4);
  u16x8 v;
  v[0] = f2bf(a.x); v[1] = f2bf(a.y); v[2] = f2bf(a.z); v[3] = f2bf(a.w);
  v[4] = f2bf(b.x); v[5] = f2bf(b.y); v[6] = f2bf(b.z); v[7] = f2bf(b.w);
  return v;
}

// direct global->LDS async copy, 16B/lane; LDS dest = wave-uniform base + lane*16
__device__ __forceinline__ void gload16(const u16* g, u16* l) {
  __builtin_amdgcn_global_load_lds((const AS1 u32*)(const void*)g,
                                   (AS3 u32*)(void*)l, 16, 0, 0);
}

// ---------------- f32 -> bf16 bulk convert: x (4M elems) then Wo (1M elems) ----------------
__global__ __launch_bounds__(256) void cvt_kernel(const float* __restrict__ x,
                                                  u16* __restrict__ xb,
                                                  const float* __restrict__ Wo,
                                                  u16* __restrict__ Wob) {
  int bid = blockIdx.x;
  const float* src; u16* dst; size_t base;
  if (bid < 2048) { src = x;  dst = xb;  base = (size_t)bid * 2048; }
  else            { src = Wo; dst = Wob; base = (size_t)(bid - 2048) * 2048; }
  size_t off = base + (size_t)threadIdx.x * 8;
  *(u16x8*)&dst[off] = cvt8(&src[off]);
}

// ---------------- Weight transpose: W(H,D,dk) f32 x3 -> WT bf16 [(t*1024 + h*64 + kk)][d] ----------------
__global__ __launch_bounds__(256) void wt_kernel(const float* __restrict__ Wq,
                                                 const float* __restrict__ Wk,
                                                 const float* __restrict__ Wv,
                                                 u16* __restrict__ WT) {
  __shared__ u16 sm[64][72];
  int bid = blockIdx.x;
  int t = bid >> 8;
  int rem = bid & 255;
  int h = rem >> 4;
  int d0 = (rem & 15) * 64;
  const float* src = (t == 0) ? Wq : (t == 1) ? Wk : Wv;
  int tid = threadIdx.x;
  for (int j = 0; j < 2; ++j) {
    int idx = tid + j * 256;
    int r = idx >> 3;
    int c0 = (idx & 7) * 8;
    *(u16x8*)&sm[r][c0] = cvt8(&src[(h * DD + d0 + r) * DKK + c0]);
  }
  __syncthreads();
  for (int j = 0; j < 2; ++j) {
    int idx = tid + j * 256;
    int r2 = idx >> 3;
    int c0 = (idx & 7) * 8;
    u16x8 vv;
    for (int i = 0; i < 8; ++i) vv[i] = sm[c0 + i][r2];
    int n = t * 1024 + h * 64 + r2;
    *(u16x8*)&WT[n * DD + d0 + c0] = vv;
  }
}

// ---------------- 128x128-tile bf16 GEMM (m97 structure + LDS granule swizzle) ----------------
__global__ __launch_bounds__(256) void gemm128(const u16* __restrict__ A,
                                               const u16* __restrict__ Bm,
                                               int mode,
                                               u16* __restrict__ o0,
                                               u16* __restrict__ o1,
                                               u16* __restrict__ o2,
                                               float* __restrict__ of) {
  __shared__ u16 As[128 * 32];
  __shared__ u16 Bs[128 * 32];
  const int K = 1024;
  int m0 = blockIdx.x * 128;
  int n0 = blockIdx.y * 128;
  int tid = threadIdx.x;
  int w = tid >> 6, l = tid & 63;
  int lg = l >> 4, lr = l & 15;
  int wr = w >> 1, wc = w & 1;

  int srow = w * 32 + (l >> 2);
  int sg = (l & 3) ^ ((l >> 3) & 3);        // pre-swizzled source granule
  const u16* gA = A + (size_t)(m0 + srow) * K + sg * 8;
  const u16* gB = Bm + (size_t)(n0 + srow) * K + sg * 8;
  u16* lA = As + w * 1024;
  u16* lB = Bs + w * 1024;
  int gsw = (lr >> 1) & 3;                  // read-side swizzle key

  f32x4 acc[4][4] = {};
  for (int kt = 0; kt < 32; ++kt) {
    int k0 = kt * 32;
    gload16(gA + k0, lA);
    gload16(gA + k0 + 16 * K, lA + 512);
    gload16(gB + k0, lB);
    gload16(gB + k0 + 16 * K, lB + 512);
    __syncthreads();
    bf16x8 a[4], b[4];
    #pragma unroll
    for (int m = 0; m < 4; ++m)
      a[m] = *(const bf16x8*)&As[(wr * 64 + m * 16 + lr) * 32 + ((lg ^ gsw) * 8)];
    #pragma unroll
    for (int n = 0; n < 4; ++n)
      b[n] = *(const bf16x8*)&Bs[(wc * 64 + n * 16 + lr) * 32 + ((lg ^ gsw) * 8)];
    #pragma unroll
    for (int m = 0; m < 4; ++m)
      #pragma unroll
      for (int n = 0; n < 4; ++n)
        acc[m][n] = __builtin_amdgcn_mfma_f32_16x16x32_bf16(a[m], b[n], acc[m][n], 0, 0, 0);
    __syncthreads();
  }

  if (mode == 1) {
    int mbase = m0 + wr * 64 + lg * 4;
    int nbase = n0 + wc * 64 + lr;
    #pragma unroll
    for (int m = 0; m < 4; ++m)
      #pragma unroll
      for (int n = 0; n < 4; ++n)
        #pragma unroll
        for (int rr = 0; rr < 4; ++rr)
          of[(size_t)(mbase + m * 16 + rr) * 1024 + nbase + n * 16] = acc[m][n][rr];
  } else {
    int t = n0 >> 10;
    int h = (((n0 & 1023) + wc * 64) >> 6);
    int bq = m0 >> 11;
    int sbase = (m0 & 2047) + wr * 64 + lg * 4;
    if (t < 2) {
      float sc = (t == 0) ? QSCALE : 1.0f;   // fold softmax scale*log2e into Q
      u16* o = (t == 0) ? o0 : o1;
      u16* op = o + (size_t)(bq * NH + h) * SQ * DKK;
      #pragma unroll
      for (int m = 0; m < 4; ++m)
        #pragma unroll
        for (int n = 0; n < 4; ++n)
          #pragma unroll
          for (int rr = 0; rr < 4; ++rr)
            op[(size_t)(sbase + m * 16 + rr) * DKK + n * 16 + lr] = f2bf(acc[m][n][rr] * sc);
    } else {
      u16* op = o2 + (size_t)(bq * NH + h) * DKK * SQ;
      #pragma unroll
      for (int m = 0; m < 4; ++m)
        #pragma unroll
        for (int n = 0; n < 4; ++n) {
          u16x4 vv;
          #pragma unroll
          for (int rr = 0; rr < 4; ++rr) vv[rr] = f2bf(acc[m][n][rr]);
          *(u16x4*)&op[(size_t)(n * 16 + lr) * SQ + sbase + m * 16] = vv;
        }
    }
  }
}

// ---------------- Flash attention v6 ----------------
// jt-loop unrolled x2 (compile-time buffer index -> static LDS addressing, mask-free main loop),
// pointer-increment staging, per-lane partial lrun (no per-tile sum shuffles).
__global__ __launch_bounds__(256) void attn_kernel(const u16* __restrict__ Q,
                                                   const u16* __restrict__ Kg,
                                                   const u16* __restrict__ Vt,
                                                   u16* __restrict__ Cc) {
  __shared__ u16 Ks[2][64 * 64];
  __shared__ u16 Vs[2][64 * 64];   // [dk][kv]
  __shared__ u16 Ps[4 * 16 * 64];  // per-wave P[q][kv], XOR-swizzled rows
  int bh = blockIdx.x;             // bh fastest -> round-robin spreads strips
  int y = blockIdx.y;
  int a = y & 7, bsel = y >> 3;
  int s = (bsel == 0) ? 2 * a : (bsel == 1) ? 2 * a + 1
        : (bsel == 2) ? 30 - 2 * a : 31 - 2 * a;   // per-CU sums = 66 tiles
  int tid = threadIdx.x;
  int w = tid >> 6, l = tid & 63;
  int lg = l >> 4, lr = l & 15;
  const u16* Qp = Q + (size_t)bh * SQ * DKK;
  const u16* Kp = Kg + (size_t)bh * SQ * DKK;
  const u16* Vp = Vt + (size_t)bh * DKK * SQ;
  int b = bh >> 4, h = bh & 15;

  // staging pointers (advance by one tile per issue)
  int lrow8 = l >> 3;
  int swz = (l & 7) ^ lrow8;
  int r7 = lr & 7;
  const u16* kS0 = Kp + (size_t)(w * 16 + lrow8) * DKK + swz * 8;
  const u16* kS1 = kS0 + 8 * DKK;
  const u16* vS0 = Vp + (size_t)(w * 16 + lrow8) * SQ + swz * 8;
  const u16* vS1 = vS0 + 8 * SQ;

  #define STAGE(BUF)                                      \
    do {                                                  \
      gload16(kS0, &Ks[BUF][(w * 16) * 64]);              \
      gload16(kS1, &Ks[BUF][(w * 16 + 8) * 64]);          \
      gload16(vS0, &Vs[BUF][(w * 16) * 64]);              \
      gload16(vS1, &Vs[BUF][(w * 16 + 8) * 64]);          \
      kS0 += 64 * DKK; kS1 += 64 * DKK;                   \
      vS0 += 64; vS1 += 64;                               \
    } while (0)

  STAGE(0);
  __syncthreads();

  int qrow = s * 64 + w * 16 + lr;
  bf16x8 qf0 = *(const bf16x8*)&Qp[(size_t)qrow * DKK + lg * 8];
  bf16x8 qf1 = *(const bf16x8*)&Qp[(size_t)qrow * DKK + 32 + lg * 8];
  f32x4 o[4] = {};
  float mrun = -1e30f, lpart = 0.f;
  int swzP = r7 << 4;
  char* PsB = (char*)Ps + w * 2048 + lr * 128;
  // lane-const LDS element bases (K and V share them: both [row][64] with row-key r7)
  int A0 = lr * 64 + (lg ^ r7) * 8;
  int A1 = lr * 64 + ((4 + lg) ^ r7) * 8;

  #define TILE(BUF, PREF, MASKED, JTV)                                        \
    do {                                                                      \
      if (PREF) STAGE(BUF ^ 1);                                               \
      float p[16];                                                            \
      __builtin_amdgcn_s_setprio(1);                                          \
      _Pragma("unroll")                                                       \
      for (int c = 0; c < 4; ++c) {                                           \
        bf16x8 k0 = *(const bf16x8*)&Ks[BUF][A0 + c * 1024];                  \
        bf16x8 k1 = *(const bf16x8*)&Ks[BUF][A1 + c * 1024];                  \
        f32x4 z = {};                                                         \
        z = __builtin_amdgcn_mfma_f32_16x16x32_bf16(k0, qf0, z, 0, 0, 0);     \
        z = __builtin_amdgcn_mfma_f32_16x16x32_bf16(k1, qf1, z, 0, 0, 0);     \
        _Pragma("unroll")                                                     \
        for (int rr = 0; rr < 4; ++rr) p[c * 4 + rr] = z[rr];                 \
      }                                                                       \
      __builtin_amdgcn_s_setprio(0);                                          \
      if (MASKED) {                                                           \
        int j0 = (JTV) * 64;                                                  \
        _Pragma("unroll")                                                     \
        for (int c = 0; c < 4; ++c)                                           \
          _Pragma("unroll")                                                   \
          for (int rr = 0; rr < 4; ++rr) {                                    \
            int kv = j0 + c * 16 + lg * 4 + rr;                               \
            if (kv > qrow) p[c * 4 + rr] = -1e30f;                            \
          }                                                                   \
      }                                                                       \
      float t0 = fmaxf(fmaxf(p[0], p[1]), p[2]);                              \
      float t1 = fmaxf(fmaxf(p[3], p[4]), p[5]);                              \
      float t2 = fmaxf(fmaxf(p[6], p[7]), p[8]);                              \
      float t3 = fmaxf(fmaxf(p[9], p[10]), p[11]);                            \
      float t4 = fmaxf(fmaxf(p[12], p[13]), p[14]);                           \
      float pm = fmaxf(fmaxf(fmaxf(t0, t1), fmaxf(t2, t3)), fmaxf(t4, p[15]));\
      pm = fmaxf(pm, __shfl_xor(pm, 16, 64));                                 \
      pm = fmaxf(pm, __shfl_xor(pm, 32, 64));                                 \
      if (__any(pm > mrun + 11.0f)) {                                         \
        float mnew = fmaxf(mrun, pm);                                         \
        float alpha = exp2f(mrun - mnew);                                     \
        mrun = mnew;                                                          \
        lpart *= alpha;                                                       \
        float af[4];                                                          \
        _Pragma("unroll")                                                     \
        for (int rr = 0; rr < 4; ++rr) af[rr] = __shfl(alpha, lg * 4 + rr, 64);\
        _Pragma("unroll")                                                     \
        for (int n = 0; n < 4; ++n)                                           \
          _Pragma("unroll")                                                   \
          for (int rr = 0; rr < 4; ++rr) o[n][rr] *= af[rr];                  \
      }                                                                       \
      float su = 0.f;                                                         \
      _Pragma("unroll")                                                       \
      for (int i = 0; i < 16; ++i) { p[i] = exp2f(p[i] - mrun); su += p[i]; } \
      lpart += su;                                                            \
      _Pragma("unroll")                                                       \
      for (int c = 0; c < 4; ++c) {                                           \
        u32x2 pk2;                                                            \
        pk2[0] = cvtpk(p[c * 4 + 0], p[c * 4 + 1]);                           \
        pk2[1] = cvtpk(p[c * 4 + 2], p[c * 4 + 3]);                           \
        *(u32x2*)(PsB + ((c * 32 + lg * 8) ^ swzP)) = pk2;                    \
      }                                                                       \
      {                                                                       \
        bf16x8 pa0 = *(const bf16x8*)(PsB + ((lg * 16) ^ swzP));              \
        bf16x8 pa1 = *(const bf16x8*)(PsB + ((64 + lg * 16) ^ swzP));         \
        __builtin_amdgcn_s_setprio(1);                                        \
        _Pragma("unroll")                                                     \
        for (int n = 0; n < 4; ++n) {                                         \
          bf16x8 vb0 = *(const bf16x8*)&Vs[BUF][A0 + n * 1024];               \
          o[n] = __builtin_amdgcn_mfma_f32_16x16x32_bf16(pa0, vb0, o[n], 0, 0, 0); \
          bf16x8 vb1 = *(const bf16x8*)&Vs[BUF][A1 + n * 1024];               \
          o[n] = __builtin_amdgcn_mfma_f32_16x16x32_bf16(pa1, vb1, o[n], 0, 0, 0); \
        }                                                                     \
        __builtin_amdgcn_s_setprio(0);                                        \
      }                                                                       \
      __syncthreads();                                                        \
    } while (0)

  int nt = s + 1;
  int jt = 0;
  while (jt + 2 < nt) {            // main loop: mask-free, static buffers
    TILE(0, 1, 0, jt);
    TILE(1, 1, 0, jt + 1);
    jt += 2;
  }
  if (nt - jt == 2) {
    TILE(0, 1, 0, jt);             // prefetches the final tile
    TILE(1, 0, 1, jt + 1);
  } else {
    TILE(0, 0, 1, jt);
  }

  float lsum = lpart;
  lsum += __shfl_xor(lsum, 16, 64);
  lsum += __shfl_xor(lsum, 32, 64);
  float lrow[4];
  #pragma unroll
  for (int rr = 0; rr < 4; ++rr) lrow[rr] = __shfl(lsum, lg * 4 + rr, 64);
  int srow = s * 64 + w * 16 + lg * 4;
  #pragma unroll
  for (int n = 0; n < 4; ++n)
    #pragma unroll
    for (int rr = 0; rr < 4; ++rr) {
      float val = o[n][rr] / lrow[rr];
      Cc[((size_t)(b * SQ + srow + rr)) * DD + h * DKK + n * 16 + lr] = f2bf(val);
    }
  #undef TILE
  #undef STAGE
}

extern "C" void kernel_launch(void* const* d_in, const int* in_sizes, int n_in,
                              void* d_out, int out_size, void* d_ws, size_t ws_size,
                              hipStream_t stream) {
  (void)in_sizes; (void)n_in; (void)out_size; (void)ws_size;
  const float* x  = (const float*)d_in[0];
  const float* Wq = (const float*)d_in[1];
  const float* Wk = (const float*)d_in[2];
  const float* Wv = (const float*)d_in[3];
  const float* Wo = (const float*)d_in[4];
  float* out = (float*)d_out;
  u16* ws = (u16*)d_ws;
  u16* WT  = ws;                    // 3,145,728 elems
  u16* Qb  = WT + 3145728;          // 4,194,304
  u16* Kb  = Qb + 4194304;          // 4,194,304
  u16* Vb  = Kb + 4194304;          // 4,194,304 (B,H,dk,S)
  u16* XC  = Vb + 4194304;          // 4,194,304 — xb (bf16 x), later aliased as Cc
  u16* Wob = XC + 4194304;          // 1,048,576

  hipLaunchKernelGGL(cvt_kernel, dim3(2560), dim3(256), 0, stream, x, XC, Wo, Wob);
  hipLaunchKernelGGL(wt_kernel, dim3(768), dim3(256), 0, stream, Wq, Wk, Wv, WT);
  hipLaunchKernelGGL(gemm128, dim3(32, 24), dim3(256), 0, stream, XC, WT, 0, Qb, Kb, Vb, (float*)nullptr);
  hipLaunchKernelGGL(attn_kernel, dim3(32, 32), dim3(256), 0, stream, Qb, Kb, Vb, XC);
  hipLaunchKernelGGL(gemm128, dim3(32, 8), dim3(256), 0, stream, XC, Wob, 1, nullptr, nullptr, nullptr, out);
}

// Round 11
// 132.661 us; speedup vs baseline: 1.1235x; 1.1235x over previous
//
#include <hip/hip_runtime.h>

typedef unsigned short u16;
typedef unsigned int u32;
typedef __bf16 bf16x8 __attribute__((ext_vector_type(8)));
typedef float f32x4 __attribute__((ext_vector_type(4)));
typedef u16 u16x8 __attribute__((ext_vector_type(8)));
typedef u16 u16x4 __attribute__((ext_vector_type(4)));
typedef u32 u32x4 __attribute__((ext_vector_type(4)));

#define NH 16
#define DKK 64
#define SQ 2048
#define DD 1024

#define AS1 __attribute__((address_space(1)))
#define AS3 __attribute__((address_space(3)))

// softmax scale folded with log2(e): (1/8) * 1.44269504
#define QSCALE 0.1803368925f

__device__ inline u16 f2bf(float f) {
  union { float f; u32 u; } v; v.f = f;
  u32 u = v.u;
  u += 0x7FFFu + ((u >> 16) & 1u);
  return (u16)(u >> 16);
}

__device__ __forceinline__ u32 cvtpk(float lo, float hi) {
  u32 r;
  asm("v_cvt_pk_bf16_f32 %0, %1, %2" : "=v"(r) : "v"(lo), "v"(hi));
  return r;
}

__device__ inline u16x8 cvt8(const float* p) {
  float4 a = *(const float4*)p;
  float4 b = *(const float4*)(p + 4);
  u16x8 v;
  v[0] = f2bf(a.x); v[1] = f2bf(a.y); v[2] = f2bf(a.z); v[3] = f2bf(a.w);
  v[4] = f2bf(b.x); v[5] = f2bf(b.y); v[6] = f2bf(b.z); v[7] = f2bf(b.w);
  return v;
}

// direct global->LDS async copy, 16B/lane; LDS dest = wave-uniform base + lane*16
__device__ __forceinline__ void gload16(const u16* g, u16* l) {
  __builtin_amdgcn_global_load_lds((const AS1 u32*)(const void*)g,
                                   (AS3 u32*)(void*)l, 16, 0, 0);
}

// ---------------- prep: f32->bf16 convert (x, Wo) + weight transpose, one launch ----------------
__global__ __launch_bounds__(256) void prep_kernel(const float* __restrict__ x,
                                                   u16* __restrict__ xb,
                                                   const float* __restrict__ Wo,
                                                   u16* __restrict__ Wob,
                                                   const float* __restrict__ Wq,
                                                   const float* __restrict__ Wk,
                                                   const float* __restrict__ Wv,
                                                   u16* __restrict__ WT) {
  __shared__ u16 sm[64][72];
  int bid = blockIdx.x;
  int tid = threadIdx.x;
  if (bid < 2560) {   // bulk convert
    const float* src; u16* dst; size_t base;
    if (bid < 2048) { src = x;  dst = xb;  base = (size_t)bid * 2048; }
    else            { src = Wo; dst = Wob; base = (size_t)(bid - 2048) * 2048; }
    size_t off = base + (size_t)tid * 8;
    *(u16x8*)&dst[off] = cvt8(&src[off]);
    return;
  }
  int wid = bid - 2560;
  int t = wid >> 8;
  int rem = wid & 255;
  int h = rem >> 4;
  int d0 = (rem & 15) * 64;
  const float* src = (t == 0) ? Wq : (t == 1) ? Wk : Wv;
  for (int j = 0; j < 2; ++j) {
    int idx = tid + j * 256;
    int r = idx >> 3;
    int c0 = (idx & 7) * 8;
    *(u16x8*)&sm[r][c0] = cvt8(&src[(h * DD + d0 + r) * DKK + c0]);
  }
  __syncthreads();
  for (int j = 0; j < 2; ++j) {
    int idx = tid + j * 256;
    int r2 = idx >> 3;
    int c0 = (idx & 7) * 8;
    u16x8 vv;
    for (int i = 0; i < 8; ++i) vv[i] = sm[c0 + i][r2];
    int n = t * 1024 + h * 64 + r2;
    *(u16x8*)&WT[n * DD + d0 + c0] = vv;
  }
}

// ---------------- 128x128-tile bf16 GEMM (m97 structure + LDS granule swizzle) ----------------
// mode 0: QKV epilogue. V^T stored with sigma-permuted S within each 64-block:
//   sigma(c*16+g*4+u) = (c>>1)*32 + g*8 + (c&1)*4 + u  (matches attn's register-P PV order)
// mode 1: f32 store.
__global__ __launch_bounds__(256) void gemm128(const u16* __restrict__ A,
                                               const u16* __restrict__ Bm,
                                               int mode,
                                               u16* __restrict__ o0,
                                               u16* __restrict__ o1,
                                               u16* __restrict__ o2,
                                               float* __restrict__ of) {
  __shared__ u16 As[128 * 32];
  __shared__ u16 Bs[128 * 32];
  const int K = 1024;
  int m0 = blockIdx.x * 128;
  int n0 = blockIdx.y * 128;
  int tid = threadIdx.x;
  int w = tid >> 6, l = tid & 63;
  int lg = l >> 4, lr = l & 15;
  int wr = w >> 1, wc = w & 1;

  int srow = w * 32 + (l >> 2);
  int sg = (l & 3) ^ ((l >> 3) & 3);        // pre-swizzled source granule
  const u16* gA = A + (size_t)(m0 + srow) * K + sg * 8;
  const u16* gB = Bm + (size_t)(n0 + srow) * K + sg * 8;
  u16* lA = As + w * 1024;
  u16* lB = Bs + w * 1024;
  int gsw = (lr >> 1) & 3;                  // read-side swizzle key

  f32x4 acc[4][4] = {};
  for (int kt = 0; kt < 32; ++kt) {
    int k0 = kt * 32;
    gload16(gA + k0, lA);
    gload16(gA + k0 + 16 * K, lA + 512);
    gload16(gB + k0, lB);
    gload16(gB + k0 + 16 * K, lB + 512);
    __syncthreads();
    bf16x8 a[4], b[4];
    #pragma unroll
    for (int m = 0; m < 4; ++m)
      a[m] = *(const bf16x8*)&As[(wr * 64 + m * 16 + lr) * 32 + ((lg ^ gsw) * 8)];
    #pragma unroll
    for (int n = 0; n < 4; ++n)
      b[n] = *(const bf16x8*)&Bs[(wc * 64 + n * 16 + lr) * 32 + ((lg ^ gsw) * 8)];
    #pragma unroll
    for (int m = 0; m < 4; ++m)
      #pragma unroll
      for (int n = 0; n < 4; ++n)
        acc[m][n] = __builtin_amdgcn_mfma_f32_16x16x32_bf16(a[m], b[n], acc[m][n], 0, 0, 0);
    __syncthreads();
  }

  if (mode == 1) {
    int mbase = m0 + wr * 64 + lg * 4;
    int nbase = n0 + wc * 64 + lr;
    #pragma unroll
    for (int m = 0; m < 4; ++m)
      #pragma unroll
      for (int n = 0; n < 4; ++n)
        #pragma unroll
        for (int rr = 0; rr < 4; ++rr)
          of[(size_t)(mbase + m * 16 + rr) * 1024 + nbase + n * 16] = acc[m][n][rr];
  } else {
    int t = n0 >> 10;
    int h = (((n0 & 1023) + wc * 64) >> 6);
    int bq = m0 >> 11;
    int sbase = (m0 & 2047) + wr * 64 + lg * 4;
    if (t < 2) {
      float sc = (t == 0) ? QSCALE : 1.0f;   // fold softmax scale*log2e into Q
      u16* o = (t == 0) ? o0 : o1;
      u16* op = o + (size_t)(bq * NH + h) * SQ * DKK;
      #pragma unroll
      for (int m = 0; m < 4; ++m)
        #pragma unroll
        for (int n = 0; n < 4; ++n)
          #pragma unroll
          for (int rr = 0; rr < 4; ++rr)
            op[(size_t)(sbase + m * 16 + rr) * DKK + n * 16 + lr] = f2bf(acc[m][n][rr] * sc);
    } else {
      // V^T with sigma-permuted S: S block base + (m>>1)*32 + lg*8 + (m&1)*4 + rr
      u16* op = o2 + (size_t)(bq * NH + h) * DKK * SQ;
      int Sb = (m0 & 2047) + wr * 64;
      #pragma unroll
      for (int m = 0; m < 4; ++m)
        #pragma unroll
        for (int n = 0; n < 4; ++n) {
          u16x4 vv;
          #pragma unroll
          for (int rr = 0; rr < 4; ++rr) vv[rr] = f2bf(acc[m][n][rr]);
          *(u16x4*)&op[(size_t)(n * 16 + lr) * SQ + Sb + (m >> 1) * 32 + lg * 8 + (m & 1) * 4] = vv;
        }
    }
  }
}

// ---------------- Flash attention v7 ----------------
// Round-9 core with the P LDS round-trip DELETED: pa0/pa1 assembled directly from
// cvt_pk words (MFMA k-permutation, V^T pre-permuted by sigma in global).
// LDS 32KB -> 5 blocks/CU.
__global__ __launch_bounds__(256) void attn_kernel(const u16* __restrict__ Q,
                                                   const u16* __restrict__ Kg,
                                                   const u16* __restrict__ Vt,
                                                   u16* __restrict__ Cc) {
  __shared__ u16 Ks[2][64 * 64];
  __shared__ u16 Vs[2][64 * 64];   // [dk][kv-sigma]
  int bh = blockIdx.x;             // bh fastest -> round-robin spreads strips
  int y = blockIdx.y;
  int a = y & 7, bsel = y >> 3;
  int s = (bsel == 0) ? 2 * a : (bsel == 1) ? 2 * a + 1
        : (bsel == 2) ? 30 - 2 * a : 31 - 2 * a;   // per-CU sums balanced
  int tid = threadIdx.x;
  int w = tid >> 6, l = tid & 63;
  int lg = l >> 4, lr = l & 15;
  const u16* Qp = Q + (size_t)bh * SQ * DKK;
  const u16* Kp = Kg + (size_t)bh * SQ * DKK;
  const u16* Vp = Vt + (size_t)bh * DKK * SQ;
  int b = bh >> 4, h = bh & 15;
  int cur = 0;

  int lrow8 = l >> 3;
  int swz = (l & 7) ^ lrow8;
  int r7 = lr & 7;
  const u16* kSrc0 = Kp + (size_t)(w * 16 + lrow8) * DKK + swz * 8;
  const u16* kSrc1 = Kp + (size_t)(w * 16 + 8 + lrow8) * DKK + swz * 8;
  const u16* vSrc0 = Vp + (size_t)(w * 16 + lrow8) * SQ + swz * 8;
  const u16* vSrc1 = Vp + (size_t)(w * 16 + 8 + lrow8) * SQ + swz * 8;

  #define STAGE(buf, j0)                                                  \
    do {                                                                  \
      gload16(kSrc0 + (size_t)(j0) * DKK, &Ks[buf][(w * 16) * 64]);       \
      gload16(kSrc1 + (size_t)(j0) * DKK, &Ks[buf][(w * 16 + 8) * 64]);   \
      gload16(vSrc0 + (j0), &Vs[buf][(w * 16) * 64]);                     \
      gload16(vSrc1 + (j0), &Vs[buf][(w * 16 + 8) * 64]);                 \
    } while (0)

  STAGE(0, 0);
  __syncthreads();

  int qrow = s * 64 + w * 16 + lr;
  bf16x8 qf0 = *(const bf16x8*)&Qp[(size_t)qrow * DKK + lg * 8];
  bf16x8 qf1 = *(const bf16x8*)&Qp[(size_t)qrow * DKK + 32 + lg * 8];
  f32x4 o[4] = {};
  float mrun = -1e30f, lrun = 0.f;

  for (int jt = 0; jt <= s; ++jt) {
    if (jt < s) STAGE(cur ^ 1, (jt + 1) * 64);

    float p[16];
    __builtin_amdgcn_s_setprio(1);
    #pragma unroll
    for (int c = 0; c < 4; ++c) {
      int R = c * 16 + lr;
      const u16* kr = &Ks[cur][R * 64];
      bf16x8 k0 = *(const bf16x8*)&kr[(lg ^ r7) * 8];
      bf16x8 k1 = *(const bf16x8*)&kr[((4 + lg) ^ r7) * 8];
      f32x4 z = {};
      z = __builtin_amdgcn_mfma_f32_16x16x32_bf16(k0, qf0, z, 0, 0, 0);
      z = __builtin_amdgcn_mfma_f32_16x16x32_bf16(k1, qf1, z, 0, 0, 0);
      #pragma unroll
      for (int rr = 0; rr < 4; ++rr) p[c * 4 + rr] = z[rr];
    }
    __builtin_amdgcn_s_setprio(0);
    if (jt == s) {  // causal mask on diagonal tile
      int j0 = jt * 64;
      #pragma unroll
      for (int c = 0; c < 4; ++c)
        #pragma unroll
        for (int rr = 0; rr < 4; ++rr) {
          int kv = j0 + c * 16 + lg * 4 + rr;
          if (kv > qrow) p[c * 4 + rr] = -1e30f;
        }
    }
    float t0 = fmaxf(fmaxf(p[0], p[1]), p[2]);
    float t1 = fmaxf(fmaxf(p[3], p[4]), p[5]);
    float t2 = fmaxf(fmaxf(p[6], p[7]), p[8]);
    float t3 = fmaxf(fmaxf(p[9], p[10]), p[11]);
    float t4 = fmaxf(fmaxf(p[12], p[13]), p[14]);
    float pm = fmaxf(fmaxf(fmaxf(t0, t1), fmaxf(t2, t3)), fmaxf(t4, p[15]));
    pm = fmaxf(pm, __shfl_xor(pm, 16, 64));
    pm = fmaxf(pm, __shfl_xor(pm, 32, 64));
    float alpha = 1.0f;
    if (__any(pm > mrun + 11.0f)) {          // defer-max
      float mnew = fmaxf(mrun, pm);
      alpha = exp2f(mrun - mnew);
      mrun = mnew;
      float af[4];
      #pragma unroll
      for (int rr = 0; rr < 4; ++rr) af[rr] = __shfl(alpha, ((l >> 4) << 2) + rr, 64);
      #pragma unroll
      for (int n = 0; n < 4; ++n)
        #pragma unroll
        for (int rr = 0; rr < 4; ++rr) o[n][rr] *= af[rr];
    }
    float su = 0.f;
    #pragma unroll
    for (int i = 0; i < 16; ++i) { p[i] = exp2f(p[i] - mrun); su += p[i]; }
    su += __shfl_xor(su, 16, 64);
    su += __shfl_xor(su, 32, 64);
    lrun = lrun * alpha + su;
    // P -> bf16 A-frags in registers (k-permutation sigma; no LDS round-trip)
    union { u32x4 w; bf16x8 v; } pk0, pk1;
    pk0.w[0] = cvtpk(p[0],  p[1]);
    pk0.w[1] = cvtpk(p[2],  p[3]);
    pk0.w[2] = cvtpk(p[4],  p[5]);
    pk0.w[3] = cvtpk(p[6],  p[7]);
    pk1.w[0] = cvtpk(p[8],  p[9]);
    pk1.w[1] = cvtpk(p[10], p[11]);
    pk1.w[2] = cvtpk(p[12], p[13]);
    pk1.w[3] = cvtpk(p[14], p[15]);
    {
      bf16x8 pa0 = pk0.v, pa1 = pk1.v;
      __builtin_amdgcn_s_setprio(1);
      #pragma unroll
      for (int n = 0; n < 4; ++n) {
        int R2 = n * 16 + lr;
        bf16x8 vb0 = *(const bf16x8*)&Vs[cur][R2 * 64 + ((lg ^ r7) * 8)];
        o[n] = __builtin_amdgcn_mfma_f32_16x16x32_bf16(pa0, vb0, o[n], 0, 0, 0);
        bf16x8 vb1 = *(const bf16x8*)&Vs[cur][R2 * 64 + (((4 + lg) ^ r7) * 8)];
        o[n] = __builtin_amdgcn_mfma_f32_16x16x32_bf16(pa1, vb1, o[n], 0, 0, 0);
      }
      __builtin_amdgcn_s_setprio(0);
    }
    __syncthreads();   // dbuf handoff (drains prefetch)
    cur ^= 1;
  }

  float lrow[4];
  #pragma unroll
  for (int rr = 0; rr < 4; ++rr) lrow[rr] = __shfl(lrun, ((l >> 4) << 2) + rr, 64);
  int srow = s * 64 + w * 16 + lg * 4;
  #pragma unroll
  for (int n = 0; n < 4; ++n)
    #pragma unroll
    for (int rr = 0; rr < 4; ++rr) {
      float val = o[n][rr] / lrow[rr];
      Cc[((size_t)(b * SQ + srow + rr)) * DD + h * DKK + n * 16 + lr] = f2bf(val);
    }
  #undef STAGE
}

extern "C" void kernel_launch(void* const* d_in, const int* in_sizes, int n_in,
                              void* d_out, int out_size, void* d_ws, size_t ws_size,
                              hipStream_t stream) {
  (void)in_sizes; (void)n_in; (void)out_size; (void)ws_size;
  const float* x  = (const float*)d_in[0];
  const float* Wq = (const float*)d_in[1];
  const float* Wk = (const float*)d_in[2];
  const float* Wv = (const float*)d_in[3];
  const float* Wo = (const float*)d_in[4];
  float* out = (float*)d_out;
  u16* ws = (u16*)d_ws;
  u16* WT  = ws;                    // 3,145,728 elems
  u16* Qb  = WT + 3145728;          // 4,194,304
  u16* Kb  = Qb + 4194304;          // 4,194,304
  u16* Vb  = Kb + 4194304;          // 4,194,304 (B,H,dk,S-sigma)
  u16* XC  = Vb + 4194304;          // 4,194,304 — xb (bf16 x), later aliased as Cc
  u16* Wob = XC + 4194304;          // 1,048,576

  hipLaunchKernelGGL(prep_kernel, dim3(3328), dim3(256), 0, stream, x, XC, Wo, Wob, Wq, Wk, Wv, WT);
  hipLaunchKernelGGL(gemm128, dim3(32, 24), dim3(256), 0, stream, XC, WT, 0, Qb, Kb, Vb, (float*)nullptr);
  hipLaunchKernelGGL(attn_kernel, dim3(32, 32), dim3(256), 0, stream, Qb, Kb, Vb, XC);
  hipLaunchKernelGGL(gemm128, dim3(32, 8), dim3(256), 0, stream, XC, Wob, 1, nullptr, nullptr, nullptr, out);
}

// Round 12
// 123.060 us; speedup vs baseline: 1.2111x; 1.0780x over previous
//
#include <hip/hip_runtime.h>

typedef unsigned short u16;
typedef unsigned int u32;
typedef __bf16 bf16x8 __attribute__((ext_vector_type(8)));
typedef float f32x4 __attribute__((ext_vector_type(4)));
typedef u16 u16x8 __attribute__((ext_vector_type(8)));
typedef u16 u16x4 __attribute__((ext_vector_type(4)));
typedef u32 u32x4 __attribute__((ext_vector_type(4)));

#define NH 16
#define DKK 64
#define SQ 2048
#define DD 1024

#define AS1 __attribute__((address_space(1)))
#define AS3 __attribute__((address_space(3)))

// softmax scale folded with log2(e): (1/8) * 1.44269504
#define QSCALE 0.1803368925f

__device__ inline u16 f2bf(float f) {
  union { float f; u32 u; } v; v.f = f;
  u32 u = v.u;
  u += 0x7FFFu + ((u >> 16) & 1u);
  return (u16)(u >> 16);
}

__device__ __forceinline__ u32 cvtpk(float lo, float hi) {
  u32 r;
  asm("v_cvt_pk_bf16_f32 %0, %1, %2" : "=v"(r) : "v"(lo), "v"(hi));
  return r;
}

__device__ inline u16x8 cvt8(const float* p) {
  float4 a = *(const float4*)p;
  float4 b = *(const float4*)(p + 4);
  u16x8 v;
  v[0] = f2bf(a.x); v[1] = f2bf(a.y); v[2] = f2bf(a.z); v[3] = f2bf(a.w);
  v[4] = f2bf(b.x); v[5] = f2bf(b.y); v[6] = f2bf(b.z); v[7] = f2bf(b.w);
  return v;
}

// direct global->LDS async copy, 16B/lane; LDS dest = wave-uniform base + lane*16
__device__ __forceinline__ void gload16(const u16* g, u16* l) {
  __builtin_amdgcn_global_load_lds((const AS1 u32*)(const void*)g,
                                   (AS3 u32*)(void*)l, 16, 0, 0);
}

// ---------------- prep: f32->bf16 convert (x, Wo) + weight transpose, one launch ----------------
__global__ __launch_bounds__(256) void prep_kernel(const float* __restrict__ x,
                                                   u16* __restrict__ xb,
                                                   const float* __restrict__ Wo,
                                                   u16* __restrict__ Wob,
                                                   const float* __restrict__ Wq,
                                                   const float* __restrict__ Wk,
                                                   const float* __restrict__ Wv,
                                                   u16* __restrict__ WT) {
  __shared__ u16 sm[64][72];
  int bid = blockIdx.x;
  int tid = threadIdx.x;
  if (bid < 2560) {   // bulk convert
    const float* src; u16* dst; size_t base;
    if (bid < 2048) { src = x;  dst = xb;  base = (size_t)bid * 2048; }
    else            { src = Wo; dst = Wob; base = (size_t)(bid - 2048) * 2048; }
    size_t off = base + (size_t)tid * 8;
    *(u16x8*)&dst[off] = cvt8(&src[off]);
    return;
  }
  int wid = bid - 2560;
  int t = wid >> 8;
  int rem = wid & 255;
  int h = rem >> 4;
  int d0 = (rem & 15) * 64;
  const float* src = (t == 0) ? Wq : (t == 1) ? Wk : Wv;
  for (int j = 0; j < 2; ++j) {
    int idx = tid + j * 256;
    int r = idx >> 3;
    int c0 = (idx & 7) * 8;
    *(u16x8*)&sm[r][c0] = cvt8(&src[(h * DD + d0 + r) * DKK + c0]);
  }
  __syncthreads();
  for (int j = 0; j < 2; ++j) {
    int idx = tid + j * 256;
    int r2 = idx >> 3;
    int c0 = (idx & 7) * 8;
    u16x8 vv;
    for (int i = 0; i < 8; ++i) vv[i] = sm[c0 + i][r2];
    int n = t * 1024 + h * 64 + r2;
    *(u16x8*)&WT[n * DD + d0 + c0] = vv;
  }
}

// ---------------- 128x128-tile bf16 GEMM, BK=64 (2 barriers per 32 MFMA) ----------------
// LDS granule full-XOR swizzle: granule g of row r stored at g^(r&7) -> conflict-free b128 reads.
// mode 0: QKV epilogue (V^T sigma-permuted per 64-block); mode 1: f32 store.
__global__ __launch_bounds__(256) void gemm128(const u16* __restrict__ A,
                                               const u16* __restrict__ Bm,
                                               int mode,
                                               u16* __restrict__ o0,
                                               u16* __restrict__ o1,
                                               u16* __restrict__ o2,
                                               float* __restrict__ of) {
  __shared__ u16 As[128 * 64];
  __shared__ u16 Bs[128 * 64];
  const int K = 1024;
  int m0 = blockIdx.x * 128;
  int n0 = blockIdx.y * 128;
  int tid = threadIdx.x;
  int w = tid >> 6, l = tid & 63;
  int lg = l >> 4, lr = l & 15;
  int wr = w >> 1, wc = w & 1;

  int srow = w * 32 + (l >> 3);           // staging row (each gload covers 8 rows)
  int sg = (l & 7) ^ ((l >> 3) & 7);      // pre-swizzled source granule (16B granules)
  const u16* gA = A + (size_t)(m0 + srow) * K + sg * 8;
  const u16* gB = Bm + (size_t)(n0 + srow) * K + sg * 8;
  u16* lA = As + (w * 32) * 64;
  u16* lB = Bs + (w * 32) * 64;
  int key = lr & 7;                       // read-side swizzle key

  f32x4 acc[4][4] = {};
  for (int kt = 0; kt < 16; ++kt) {
    int k0 = kt * 64;
    #pragma unroll
    for (int g = 0; g < 4; ++g) {
      gload16(gA + k0 + g * 8 * K, lA + g * 8 * 64);
      gload16(gB + k0 + g * 8 * K, lB + g * 8 * 64);
    }
    __syncthreads();
    #pragma unroll
    for (int kk = 0; kk < 2; ++kk) {
      bf16x8 a[4], b[4];
      #pragma unroll
      for (int m = 0; m < 4; ++m)
        a[m] = *(const bf16x8*)&As[(wr * 64 + m * 16 + lr) * 64 + (((kk * 4 + lg) ^ key) * 8)];
      #pragma unroll
      for (int n = 0; n < 4; ++n)
        b[n] = *(const bf16x8*)&Bs[(wc * 64 + n * 16 + lr) * 64 + (((kk * 4 + lg) ^ key) * 8)];
      #pragma unroll
      for (int m = 0; m < 4; ++m)
        #pragma unroll
        for (int n = 0; n < 4; ++n)
          acc[m][n] = __builtin_amdgcn_mfma_f32_16x16x32_bf16(a[m], b[n], acc[m][n], 0, 0, 0);
    }
    __syncthreads();
  }

  if (mode == 1) {
    int mbase = m0 + wr * 64 + lg * 4;
    int nbase = n0 + wc * 64 + lr;
    #pragma unroll
    for (int m = 0; m < 4; ++m)
      #pragma unroll
      for (int n = 0; n < 4; ++n)
        #pragma unroll
        for (int rr = 0; rr < 4; ++rr)
          of[(size_t)(mbase + m * 16 + rr) * 1024 + nbase + n * 16] = acc[m][n][rr];
  } else {
    int t = n0 >> 10;
    int h = (((n0 & 1023) + wc * 64) >> 6);
    int bq = m0 >> 11;
    int sbase = (m0 & 2047) + wr * 64 + lg * 4;
    if (t < 2) {
      float sc = (t == 0) ? QSCALE : 1.0f;   // fold softmax scale*log2e into Q
      u16* o = (t == 0) ? o0 : o1;
      u16* op = o + (size_t)(bq * NH + h) * SQ * DKK;
      #pragma unroll
      for (int m = 0; m < 4; ++m)
        #pragma unroll
        for (int n = 0; n < 4; ++n)
          #pragma unroll
          for (int rr = 0; rr < 4; ++rr)
            op[(size_t)(sbase + m * 16 + rr) * DKK + n * 16 + lr] = f2bf(acc[m][n][rr] * sc);
    } else {
      // V^T with sigma-permuted S: S block base + (m>>1)*32 + lg*8 + (m&1)*4 + rr
      u16* op = o2 + (size_t)(bq * NH + h) * DKK * SQ;
      int Sb = (m0 & 2047) + wr * 64;
      #pragma unroll
      for (int m = 0; m < 4; ++m)
        #pragma unroll
        for (int n = 0; n < 4; ++n) {
          u16x4 vv;
          #pragma unroll
          for (int rr = 0; rr < 4; ++rr) vv[rr] = f2bf(acc[m][n][rr]);
          *(u16x4*)&op[(size_t)(n * 16 + lr) * SQ + Sb + (m >> 1) * 32 + lg * 8 + (m & 1) * 4] = vv;
        }
    }
  }
}

// ---------------- Flash attention v8 ----------------
// v7 core (register-P sigma PV, zero bank conflicts) + per-lane partial lrun
// (no per-tile sum shuffles; cross-lane reduce once per strip).
__global__ __launch_bounds__(256) void attn_kernel(const u16* __restrict__ Q,
                                                   const u16* __restrict__ Kg,
                                                   const u16* __restrict__ Vt,
                                                   u16* __restrict__ Cc) {
  __shared__ u16 Ks[2][64 * 64];
  __shared__ u16 Vs[2][64 * 64];   // [dk][kv-sigma]
  int bh = blockIdx.x;             // bh fastest -> round-robin spreads strips
  int y = blockIdx.y;
  int a = y & 7, bsel = y >> 3;
  int s = (bsel == 0) ? 2 * a : (bsel == 1) ? 2 * a + 1
        : (bsel == 2) ? 30 - 2 * a : 31 - 2 * a;   // per-CU sums balanced
  int tid = threadIdx.x;
  int w = tid >> 6, l = tid & 63;
  int lg = l >> 4, lr = l & 15;
  const u16* Qp = Q + (size_t)bh * SQ * DKK;
  const u16* Kp = Kg + (size_t)bh * SQ * DKK;
  const u16* Vp = Vt + (size_t)bh * DKK * SQ;
  int b = bh >> 4, h = bh & 15;
  int cur = 0;

  int lrow8 = l >> 3;
  int swz = (l & 7) ^ lrow8;
  int r7 = lr & 7;
  const u16* kSrc0 = Kp + (size_t)(w * 16 + lrow8) * DKK + swz * 8;
  const u16* kSrc1 = Kp + (size_t)(w * 16 + 8 + lrow8) * DKK + swz * 8;
  const u16* vSrc0 = Vp + (size_t)(w * 16 + lrow8) * SQ + swz * 8;
  const u16* vSrc1 = Vp + (size_t)(w * 16 + 8 + lrow8) * SQ + swz * 8;

  #define STAGE(buf, j0)                                                  \
    do {                                                                  \
      gload16(kSrc0 + (size_t)(j0) * DKK, &Ks[buf][(w * 16) * 64]);       \
      gload16(kSrc1 + (size_t)(j0) * DKK, &Ks[buf][(w * 16 + 8) * 64]);   \
      gload16(vSrc0 + (j0), &Vs[buf][(w * 16) * 64]);                     \
      gload16(vSrc1 + (j0), &Vs[buf][(w * 16 + 8) * 64]);                 \
    } while (0)

  STAGE(0, 0);
  __syncthreads();

  int qrow = s * 64 + w * 16 + lr;
  bf16x8 qf0 = *(const bf16x8*)&Qp[(size_t)qrow * DKK + lg * 8];
  bf16x8 qf1 = *(const bf16x8*)&Qp[(size_t)qrow * DKK + 32 + lg * 8];
  f32x4 o[4] = {};
  float mrun = -1e30f, lpart = 0.f;

  for (int jt = 0; jt <= s; ++jt) {
    if (jt < s) STAGE(cur ^ 1, (jt + 1) * 64);

    float p[16];
    __builtin_amdgcn_s_setprio(1);
    #pragma unroll
    for (int c = 0; c < 4; ++c) {
      int R = c * 16 + lr;
      const u16* kr = &Ks[cur][R * 64];
      bf16x8 k0 = *(const bf16x8*)&kr[(lg ^ r7) * 8];
      bf16x8 k1 = *(const bf16x8*)&kr[((4 + lg) ^ r7) * 8];
      f32x4 z = {};
      z = __builtin_amdgcn_mfma_f32_16x16x32_bf16(k0, qf0, z, 0, 0, 0);
      z = __builtin_amdgcn_mfma_f32_16x16x32_bf16(k1, qf1, z, 0, 0, 0);
      #pragma unroll
      for (int rr = 0; rr < 4; ++rr) p[c * 4 + rr] = z[rr];
    }
    __builtin_amdgcn_s_setprio(0);
    if (jt == s) {  // causal mask on diagonal tile
      int j0 = jt * 64;
      #pragma unroll
      for (int c = 0; c < 4; ++c)
        #pragma unroll
        for (int rr = 0; rr < 4; ++rr) {
          int kv = j0 + c * 16 + lg * 4 + rr;
          if (kv > qrow) p[c * 4 + rr] = -1e30f;
        }
    }
    float t0 = fmaxf(fmaxf(p[0], p[1]), p[2]);
    float t1 = fmaxf(fmaxf(p[3], p[4]), p[5]);
    float t2 = fmaxf(fmaxf(p[6], p[7]), p[8]);
    float t3 = fmaxf(fmaxf(p[9], p[10]), p[11]);
    float t4 = fmaxf(fmaxf(p[12], p[13]), p[14]);
    float pm = fmaxf(fmaxf(fmaxf(t0, t1), fmaxf(t2, t3)), fmaxf(t4, p[15]));
    pm = fmaxf(pm, __shfl_xor(pm, 16, 64));
    pm = fmaxf(pm, __shfl_xor(pm, 32, 64));
    if (__any(pm > mrun + 11.0f)) {          // defer-max
      float mnew = fmaxf(mrun, pm);
      float alpha = exp2f(mrun - mnew);
      mrun = mnew;
      lpart *= alpha;
      float af[4];
      #pragma unroll
      for (int rr = 0; rr < 4; ++rr) af[rr] = __shfl(alpha, lg * 4 + rr, 64);
      #pragma unroll
      for (int n = 0; n < 4; ++n)
        #pragma unroll
        for (int rr = 0; rr < 4; ++rr) o[n][rr] *= af[rr];
    }
    float su = 0.f;
    #pragma unroll
    for (int i = 0; i < 16; ++i) { p[i] = exp2f(p[i] - mrun); su += p[i]; }
    lpart += su;
    // P -> bf16 A-frags in registers (k-permutation sigma; no LDS round-trip)
    union { u32x4 w; bf16x8 v; } pk0, pk1;
    pk0.w[0] = cvtpk(p[0],  p[1]);
    pk0.w[1] = cvtpk(p[2],  p[3]);
    pk0.w[2] = cvtpk(p[4],  p[5]);
    pk0.w[3] = cvtpk(p[6],  p[7]);
    pk1.w[0] = cvtpk(p[8],  p[9]);
    pk1.w[1] = cvtpk(p[10], p[11]);
    pk1.w[2] = cvtpk(p[12], p[13]);
    pk1.w[3] = cvtpk(p[14], p[15]);
    {
      bf16x8 pa0 = pk0.v, pa1 = pk1.v;
      __builtin_amdgcn_s_setprio(1);
      #pragma unroll
      for (int n = 0; n < 4; ++n) {
        int R2 = n * 16 + lr;
        bf16x8 vb0 = *(const bf16x8*)&Vs[cur][R2 * 64 + ((lg ^ r7) * 8)];
        o[n] = __builtin_amdgcn_mfma_f32_16x16x32_bf16(pa0, vb0, o[n], 0, 0, 0);
        bf16x8 vb1 = *(const bf16x8*)&Vs[cur][R2 * 64 + (((4 + lg) ^ r7) * 8)];
        o[n] = __builtin_amdgcn_mfma_f32_16x16x32_bf16(pa1, vb1, o[n], 0, 0, 0);
      }
      __builtin_amdgcn_s_setprio(0);
    }
    __syncthreads();   // dbuf handoff (drains prefetch)
    cur ^= 1;
  }

  float lsum = lpart;
  lsum += __shfl_xor(lsum, 16, 64);
  lsum += __shfl_xor(lsum, 32, 64);
  float lrow[4];
  #pragma unroll
  for (int rr = 0; rr < 4; ++rr) lrow[rr] = __shfl(lsum, lg * 4 + rr, 64);
  int srow = s * 64 + w * 16 + lg * 4;
  #pragma unroll
  for (int n = 0; n < 4; ++n)
    #pragma unroll
    for (int rr = 0; rr < 4; ++rr) {
      float val = o[n][rr] / lrow[rr];
      Cc[((size_t)(b * SQ + srow + rr)) * DD + h * DKK + n * 16 + lr] = f2bf(val);
    }
  #undef STAGE
}

extern "C" void kernel_launch(void* const* d_in, const int* in_sizes, int n_in,
                              void* d_out, int out_size, void* d_ws, size_t ws_size,
                              hipStream_t stream) {
  (void)in_sizes; (void)n_in; (void)out_size; (void)ws_size;
  const float* x  = (const float*)d_in[0];
  const float* Wq = (const float*)d_in[1];
  const float* Wk = (const float*)d_in[2];
  const float* Wv = (const float*)d_in[3];
  const float* Wo = (const float*)d_in[4];
  float* out = (float*)d_out;
  u16* ws = (u16*)d_ws;
  u16* WT  = ws;                    // 3,145,728 elems
  u16* Qb  = WT + 3145728;          // 4,194,304
  u16* Kb  = Qb + 4194304;          // 4,194,304
  u16* Vb  = Kb + 4194304;          // 4,194,304 (B,H,dk,S-sigma)
  u16* XC  = Vb + 4194304;          // 4,194,304 — xb (bf16 x), later aliased as Cc
  u16* Wob = XC + 4194304;          // 1,048,576

  hipLaunchKernelGGL(prep_kernel, dim3(3328), dim3(256), 0, stream, x, XC, Wo, Wob, Wq, Wk, Wv, WT);
  hipLaunchKernelGGL(gemm128, dim3(32, 24), dim3(256), 0, stream, XC, WT, 0, Qb, Kb, Vb, (float*)nullptr);
  hipLaunchKernelGGL(attn_kernel, dim3(32, 32), dim3(256), 0, stream, Qb, Kb, Vb, XC);
  hipLaunchKernelGGL(gemm128, dim3(32, 8), dim3(256), 0, stream, XC, Wob, 1, nullptr, nullptr, nullptr, out);
}